// Round 7
// baseline (1402.897 us; speedup 1.0000x reference)
//
#include <hip/hip_runtime.h>

#define H 128
#define NPB 64       // nodes per bucket (LDS acc = NPB*H*4 = 32 KB)
#define NB_MAX 2048  // max buckets supported by fill/count LDS
#define FILL_CH 8192 // edges per bucket_fill block

// fp32 -> bf16 round-to-nearest-even
static __device__ __forceinline__ unsigned short f2bf(float f) {
  unsigned u = __float_as_uint(f);
  u += 0x7FFFu + ((u >> 16) & 1u);
  return (unsigned short)(u >> 16);
}

// ---------------------------------------------------------------------------
// GEMM: X0 = notes @ w, register-blocked (R4-proven).
// x0 stored bf16; rows >= garment written fp32 to output tail.
// ---------------------------------------------------------------------------
__global__ __launch_bounds__(256) void gemm_kernel(
    const float* __restrict__ notes, const float* __restrict__ w,
    const int* __restrict__ g_ptr, unsigned short* __restrict__ x0h,
    float* __restrict__ out, int n_nodes) {
  __shared__ float wtile[32 * H];   // 16 KB
  __shared__ float ntile[64 * 32];  // 8 KB
  const int tid = threadIdx.x;
  const int tx = tid & 31;
  const int ty = tid >> 5;
  const int rowBlk = blockIdx.x * 64;
  const int g = *g_ptr;

  float acc[8][4];
#pragma unroll
  for (int i = 0; i < 8; ++i)
#pragma unroll
    for (int j = 0; j < 4; ++j) acc[i][j] = 0.f;

  for (int kc = 0; kc < H; kc += 32) {
    __syncthreads();
    {
      const float4* wg = (const float4*)(w + (size_t)kc * H);
      float4* wl = (float4*)wtile;
#pragma unroll
      for (int i = 0; i < 4; ++i) wl[tid + i * 256] = wg[tid + i * 256];
    }
    {
      float4* nl = (float4*)ntile;
#pragma unroll
      for (int i = 0; i < 2; ++i) {
        const int idx = tid + i * 256;
        const int row = idx >> 3;
        const int q = idx & 7;
        const int rr = min(rowBlk + row, n_nodes - 1);
        nl[idx] = *(const float4*)(notes + (size_t)rr * H + kc + q * 4);
      }
    }
    __syncthreads();
#pragma unroll 8
    for (int kk = 0; kk < 32; ++kk) {
      const float4 b4 = *(const float4*)&wtile[kk * H + tx * 4];
      float a[8];
#pragma unroll
      for (int i = 0; i < 8; ++i) a[i] = ntile[(ty * 8 + i) * 32 + kk];
#pragma unroll
      for (int i = 0; i < 8; ++i) {
        acc[i][0] += a[i] * b4.x;
        acc[i][1] += a[i] * b4.y;
        acc[i][2] += a[i] * b4.z;
        acc[i][3] += a[i] * b4.w;
      }
    }
  }

#pragma unroll
  for (int i = 0; i < 8; ++i) {
    const int r = rowBlk + ty * 8 + i;
    if (r < n_nodes) {
      ushort4 h;
      h.x = f2bf(acc[i][0]);
      h.y = f2bf(acc[i][1]);
      h.z = f2bf(acc[i][2]);
      h.w = f2bf(acc[i][3]);
      *(ushort4*)(x0h + (size_t)r * H + tx * 4) = h;
      if (r >= g) {
        float4 v;
        v.x = acc[i][0]; v.y = acc[i][1]; v.z = acc[i][2]; v.w = acc[i][3];
        *(float4*)(out + (size_t)(n_nodes + r - g) * H + tx * 4) = v;
      }
    }
  }
}

// ---------------------------------------------------------------------------
// Bucket count: LDS histogram of src>>6, coalesced global flush.
// ---------------------------------------------------------------------------
__global__ __launch_bounds__(256) void bucket_count_kernel(
    const int* __restrict__ esrc, int* __restrict__ bucketCount, int n_edges,
    int nb) {
  __shared__ int cnt[NB_MAX];
  for (int i = threadIdx.x; i < nb; i += 256) cnt[i] = 0;
  __syncthreads();
  int i = blockIdx.x * 256 + threadIdx.x;
  const int stride = gridDim.x * 256;
  for (; i < n_edges; i += stride) atomicAdd(&cnt[esrc[i] >> 6], 1);
  __syncthreads();
  for (int j = threadIdx.x; j < nb; j += 256) {
    const int c = cnt[j];
    if (c) atomicAdd(&bucketCount[j], c);
  }
}

// ---------------------------------------------------------------------------
// Bucket scan: single block, 256 threads, each owns a contiguous segment.
// Writes exclusive prefix into bucketBase (nb+1) and bucketCursor.
// ---------------------------------------------------------------------------
__global__ __launch_bounds__(256) void bucket_scan_kernel(
    const int* __restrict__ bucketCount, int* __restrict__ bucketBase,
    int* __restrict__ bucketCursor, int nb) {
  __shared__ int part[256];
  const int t = threadIdx.x;
  const int K = (nb + 255) / 256;
  const int lo = t * K;
  const int hi = min(lo + K, nb);
  int sum = 0;
  for (int i = lo; i < hi; ++i) sum += bucketCount[i];
  part[t] = sum;
  __syncthreads();
  for (int o = 1; o < 256; o <<= 1) {
    const int tv = (t >= o) ? part[t - o] : 0;
    __syncthreads();
    part[t] += tv;
    __syncthreads();
  }
  int run = (t == 0) ? 0 : part[t - 1];
  for (int i = lo; i < hi; ++i) {
    bucketBase[i] = run;
    bucketCursor[i] = run;
    run += bucketCount[i];
  }
  if (t == 255) bucketBase[nb] = part[255];
}

// ---------------------------------------------------------------------------
// Bucket fill: per-block LDS count -> one coalesced RT atomic per bucket ->
// LDS-cursor placement. Entry: x = (src&63)<<25 | dst, y = weight bits.
// ---------------------------------------------------------------------------
__global__ __launch_bounds__(256) void bucket_fill_kernel(
    const int* __restrict__ esrc, const int* __restrict__ edst,
    const float* __restrict__ ew, int* __restrict__ bucketCursor,
    int2* __restrict__ sedge, int n_edges, int nb) {
  __shared__ int cnt[NB_MAX];
  __shared__ int curs[NB_MAX];
  const int t = threadIdx.x;
  const int base = blockIdx.x * FILL_CH;
  for (int i = t; i < nb; i += 256) cnt[i] = 0;
  __syncthreads();
  for (int k = 0; k < FILL_CH / 256; ++k) {
    const int e = base + k * 256 + t;
    if (e < n_edges) atomicAdd(&cnt[esrc[e] >> 6], 1);
  }
  __syncthreads();
  for (int i = t; i < nb; i += 256) {
    const int c = cnt[i];
    curs[i] = c ? atomicAdd(&bucketCursor[i], c) : 0;
  }
  __syncthreads();
  for (int k = 0; k < FILL_CH / 256; ++k) {
    const int e = base + k * 256 + t;
    if (e < n_edges) {
      const int s = esrc[e];
      const int pos = atomicAdd(&curs[s >> 6], 1);
      int2 pk;
      pk.x = ((s & 63) << 25) | edst[e];
      pk.y = __float_as_int(ew[e]);
      sedge[pos] = pk;
    }
  }
}

// ---------------------------------------------------------------------------
// Bucket gather: one block per bucket. 32 KB LDS fp32 accumulator for 64
// nodes x 128 feats. Wave-per-edge (2-way ILP): coalesced 256B bf16 row read,
// 2 LDS atomic adds per lane (2-way bank aliasing = free). Epilogue fused.
// ---------------------------------------------------------------------------
__global__ __launch_bounds__(256) void bucket_gather_kernel(
    const int* __restrict__ bucketBase, const int2* __restrict__ sedge,
    const unsigned short* __restrict__ x0h, const float* __restrict__ b,
    float* __restrict__ out, int n_nodes) {
  __shared__ float acc[NPB * H];  // 32 KB
  const int t = threadIdx.x;
  const int lane = t & 63;
  const int wv = t >> 6;
  {
    float4* a4 = (float4*)acc;
    for (int i = t; i < NPB * H / 4; i += 256)
      a4[i] = make_float4(0.f, 0.f, 0.f, 0.f);
  }
  __syncthreads();
  const int beg = bucketBase[blockIdx.x];
  const int end = bucketBase[blockIdx.x + 1];
  const unsigned* __restrict__ x0u = (const unsigned*)x0h;

  for (int e = beg + wv * 2; e < end; e += 8) {
    const int2 p0 = sedge[e];
    const bool has1 = (e + 1) < end;
    const int2 p1 = has1 ? sedge[e + 1] : make_int2(0, 0);  // w=0 -> no-op
    const unsigned u0 = x0u[(size_t)(p0.x & 0x1FFFFFF) * 64 + lane];
    const unsigned u1 = x0u[(size_t)(p1.x & 0x1FFFFFF) * 64 + lane];
    const float w0 = __int_as_float(p0.y);
    const float w1 = __int_as_float(p1.y);
    const int s0 = (p0.x >> 25) & 63;
    const int s1 = (p1.x >> 25) & 63;
    atomicAdd(&acc[s0 * H + lane * 2], __uint_as_float(u0 << 16) * w0);
    atomicAdd(&acc[s0 * H + lane * 2 + 1],
              __uint_as_float(u0 & 0xFFFF0000u) * w0);
    atomicAdd(&acc[s1 * H + lane * 2], __uint_as_float(u1 << 16) * w1);
    atomicAdd(&acc[s1 * H + lane * 2 + 1],
              __uint_as_float(u1 & 0xFFFF0000u) * w1);
  }
  __syncthreads();

  const int nodeBase = blockIdx.x * NPB;
  float2* out2 = (float2*)out;
  const float2* b2 = (const float2*)b;
  for (int i = t; i < NPB * H / 2; i += 256) {
    const int nl = i >> 6;   // H/2 = 64 float2 per node
    const int c2 = i & 63;
    const int node = nodeBase + nl;
    if (node < n_nodes) {
      const float2 v = *(const float2*)&acc[nl * H + c2 * 2];
      const float2 bb = b2[c2];
      float2 r;
      r.x = fmaxf(v.x + bb.x, 0.f);
      r.y = fmaxf(v.y + bb.y, 0.f);
      out2[(size_t)node * 64 + c2] = r;
    }
  }
}

// ---------------------------------------------------------------------------
// Fallback path (constraints violated): atomic scatter + epilogue.
// ---------------------------------------------------------------------------
__global__ __launch_bounds__(256) void scatter_kernel(
    const int* __restrict__ esrc, const int* __restrict__ edst,
    const float* __restrict__ ew, const unsigned short* __restrict__ x0h,
    float* __restrict__ acc, int n_edges) {
  const int lane = threadIdx.x & 63;
  const int waveId = blockIdx.x * (blockDim.x >> 6) + (threadIdx.x >> 6);
  const int nWaves = gridDim.x * (blockDim.x >> 6);
  const unsigned* __restrict__ x0u = (const unsigned*)x0h;
  for (int e = waveId; e < n_edges; e += nWaves) {
    const int s = esrc[e];
    const int d = edst[e];
    const float wt = ew[e];
    const unsigned u = x0u[(size_t)d * 64 + lane];
    float* p = acc + (size_t)s * H + lane * 2;
    atomicAdd(p, __uint_as_float(u << 16) * wt);
    atomicAdd(p + 1, __uint_as_float(u & 0xFFFF0000u) * wt);
  }
}

__global__ __launch_bounds__(256) void epilogue_kernel(
    float* __restrict__ out, const float* __restrict__ b, int n4) {
  const int i = blockIdx.x * blockDim.x + threadIdx.x;
  if (i >= n4) return;
  float4* o4 = (float4*)out;
  const float4* b4 = (const float4*)b;
  float4 v = o4[i];
  const float4 bb = b4[i & 31];
  v.x = fmaxf(v.x + bb.x, 0.f);
  v.y = fmaxf(v.y + bb.y, 0.f);
  v.z = fmaxf(v.z + bb.z, 0.f);
  v.w = fmaxf(v.w + bb.w, 0.f);
  o4[i] = v;
}

extern "C" void kernel_launch(void* const* d_in, const int* in_sizes, int n_in,
                              void* d_out, int out_size, void* d_ws, size_t ws_size,
                              hipStream_t stream) {
  const float* notes = (const float*)d_in[0];
  const float* w     = (const float*)d_in[1];
  const float* b     = (const float*)d_in[2];
  const int*   esrc  = (const int*)d_in[3];
  const int*   edst  = (const int*)d_in[4];
  const float* ew    = (const float*)d_in[5];
  const int*   gptr  = (const int*)d_in[6];

  const int n_nodes = in_sizes[0] / H;
  const int n_edges = in_sizes[3];
  float* out = (float*)d_out;

  const int nb = (n_nodes + NPB - 1) / NPB;

  // Workspace carve-up (256B-aligned regions).
  char* ws = (char*)d_ws;
  size_t p = 0;
  auto alloc = [&](size_t bytes) -> char* {
    char* cur = ws + p;
    p = (p + bytes + 255) & ~(size_t)255;
    return cur;
  };
  unsigned short* x0h = (unsigned short*)alloc((size_t)n_nodes * H * 2);
  int*  bucketCount  = (int*)alloc((size_t)nb * sizeof(int));
  int*  bucketBase   = (int*)alloc(((size_t)nb + 1) * sizeof(int));
  int*  bucketCursor = (int*)alloc((size_t)nb * sizeof(int));
  int2* sedge        = (int2*)alloc((size_t)n_edges * sizeof(int2));
  const bool ok = (p <= ws_size) && (nb <= NB_MAX) && (n_nodes < (1 << 25));

  // GEMM (also writes concat tail rows fp32; x0 stored bf16).
  gemm_kernel<<<(n_nodes + 63) / 64, 256, 0, stream>>>(notes, w, gptr, x0h, out,
                                                       n_nodes);

  if (ok) {
    hipMemsetAsync(bucketCount, 0, (size_t)nb * sizeof(int), stream);
    bucket_count_kernel<<<256, 256, 0, stream>>>(esrc, bucketCount, n_edges,
                                                 nb);
    bucket_scan_kernel<<<1, 256, 0, stream>>>(bucketCount, bucketBase,
                                              bucketCursor, nb);
    bucket_fill_kernel<<<(n_edges + FILL_CH - 1) / FILL_CH, 256, 0, stream>>>(
        esrc, edst, ew, bucketCursor, sedge, n_edges, nb);
    bucket_gather_kernel<<<nb, 256, 0, stream>>>(bucketBase, sedge, x0h, b, out,
                                                 n_nodes);
  } else {
    hipMemsetAsync(d_out, 0, (size_t)n_nodes * H * sizeof(float), stream);
    scatter_kernel<<<2048, 256, 0, stream>>>(esrc, edst, ew, x0h, out, n_edges);
    const int n4 = n_nodes * H / 4;
    epilogue_kernel<<<(n4 + 255) / 256, 256, 0, stream>>>(out, b, n4);
  }
}

// Round 8
// 306.877 us; speedup vs baseline: 4.5715x; 4.5715x over previous
//
#include <hip/hip_runtime.h>

#define H 128
#define NPB 256       // nodes per coarse bucket
#define NB_MAX 1024   // max buckets (LDS arrays) -> n_nodes <= 262144
#define FILL_CH 4096  // edges per bucket_fill block

// fp32 -> bf16 round-to-nearest-even
static __device__ __forceinline__ unsigned short f2bf(float f) {
  unsigned u = __float_as_uint(f);
  u += 0x7FFFu + ((u >> 16) & 1u);
  return (unsigned short)(u >> 16);
}

// ---------------------------------------------------------------------------
// GEMM: X0 = notes @ w, register-blocked (R4-proven, verbatim).
// x0 stored bf16; rows >= garment written fp32 to output tail.
// ---------------------------------------------------------------------------
__global__ __launch_bounds__(256) void gemm_kernel(
    const float* __restrict__ notes, const float* __restrict__ w,
    const int* __restrict__ g_ptr, unsigned short* __restrict__ x0h,
    float* __restrict__ out, int n_nodes) {
  __shared__ float wtile[32 * H];   // 16 KB
  __shared__ float ntile[64 * 32];  // 8 KB
  const int tid = threadIdx.x;
  const int tx = tid & 31;
  const int ty = tid >> 5;
  const int rowBlk = blockIdx.x * 64;
  const int g = *g_ptr;

  float acc[8][4];
#pragma unroll
  for (int i = 0; i < 8; ++i)
#pragma unroll
    for (int j = 0; j < 4; ++j) acc[i][j] = 0.f;

  for (int kc = 0; kc < H; kc += 32) {
    __syncthreads();
    {
      const float4* wg = (const float4*)(w + (size_t)kc * H);
      float4* wl = (float4*)wtile;
#pragma unroll
      for (int i = 0; i < 4; ++i) wl[tid + i * 256] = wg[tid + i * 256];
    }
    {
      float4* nl = (float4*)ntile;
#pragma unroll
      for (int i = 0; i < 2; ++i) {
        const int idx = tid + i * 256;
        const int row = idx >> 3;
        const int q = idx & 7;
        const int rr = min(rowBlk + row, n_nodes - 1);
        nl[idx] = *(const float4*)(notes + (size_t)rr * H + kc + q * 4);
      }
    }
    __syncthreads();
#pragma unroll 8
    for (int kk = 0; kk < 32; ++kk) {
      const float4 b4 = *(const float4*)&wtile[kk * H + tx * 4];
      float a[8];
#pragma unroll
      for (int i = 0; i < 8; ++i) a[i] = ntile[(ty * 8 + i) * 32 + kk];
#pragma unroll
      for (int i = 0; i < 8; ++i) {
        acc[i][0] += a[i] * b4.x;
        acc[i][1] += a[i] * b4.y;
        acc[i][2] += a[i] * b4.z;
        acc[i][3] += a[i] * b4.w;
      }
    }
  }

#pragma unroll
  for (int i = 0; i < 8; ++i) {
    const int r = rowBlk + ty * 8 + i;
    if (r < n_nodes) {
      ushort4 h;
      h.x = f2bf(acc[i][0]);
      h.y = f2bf(acc[i][1]);
      h.z = f2bf(acc[i][2]);
      h.w = f2bf(acc[i][3]);
      *(ushort4*)(x0h + (size_t)r * H + tx * 4) = h;
      if (r >= g) {
        float4 v;
        v.x = acc[i][0]; v.y = acc[i][1]; v.z = acc[i][2]; v.w = acc[i][3];
        *(float4*)(out + (size_t)(n_nodes + r - g) * H + tx * 4) = v;
      }
    }
  }
}

// ---------------------------------------------------------------------------
// Bucket count: LDS histogram of src>>8, coalesced fire-and-forget flush.
// ---------------------------------------------------------------------------
__global__ __launch_bounds__(256) void bucket_count_kernel(
    const int* __restrict__ esrc, int* __restrict__ bucketCount, int n_edges,
    int nb) {
  __shared__ int cnt[NB_MAX];
  for (int i = threadIdx.x; i < nb; i += 256) cnt[i] = 0;
  __syncthreads();
  int i = blockIdx.x * 256 + threadIdx.x;
  const int stride = gridDim.x * 256;
  for (; i < n_edges; i += stride) atomicAdd(&cnt[esrc[i] >> 8], 1);
  __syncthreads();
  for (int j = threadIdx.x; j < nb; j += 256) {
    const int c = cnt[j];
    if (c) atomicAdd(&bucketCount[j], c);
  }
}

// ---------------------------------------------------------------------------
// Bucket scan: single block; exclusive prefix -> bucketBase (nb+1), cursor.
// Also writes off[n_nodes] = n_edges.
// ---------------------------------------------------------------------------
__global__ __launch_bounds__(256) void bucket_scan_kernel(
    const int* __restrict__ bucketCount, int* __restrict__ bucketBase,
    int* __restrict__ bucketCursor, int* __restrict__ off, int nb,
    int n_nodes, int n_edges) {
  __shared__ int part[256];
  const int t = threadIdx.x;
  const int K = (nb + 255) / 256;
  const int lo = t * K;
  const int hi = min(lo + K, nb);
  int sum = 0;
  for (int i = lo; i < hi; ++i) sum += bucketCount[i];
  part[t] = sum;
  __syncthreads();
  for (int o = 1; o < 256; o <<= 1) {
    const int tv = (t >= o) ? part[t - o] : 0;
    __syncthreads();
    part[t] += tv;
    __syncthreads();
  }
  int run = (t == 0) ? 0 : part[t - 1];
  for (int i = lo; i < hi; ++i) {
    bucketBase[i] = run;
    bucketCursor[i] = run;
    run += bucketCount[i];
  }
  if (t == 255) {
    bucketBase[nb] = part[255];
    off[n_nodes] = n_edges;
  }
}

// ---------------------------------------------------------------------------
// Bucket fill: per-block LDS count -> scan -> one coalesced RT atomic per
// (block,bucket) -> LDS-staged grouping -> contiguous-run global flush.
// Int atomics only. sedge entry: {dst, weight-bits}; srcloc: src & 255.
// ---------------------------------------------------------------------------
__global__ __launch_bounds__(256) void bucket_fill_kernel(
    const int* __restrict__ esrc, const int* __restrict__ edst,
    const float* __restrict__ ew, int* __restrict__ bucketCursor,
    int2* __restrict__ sedge, unsigned char* __restrict__ srcloc, int n_edges,
    int nb) {
  __shared__ int2 stage[FILL_CH];            // 32 KB
  __shared__ unsigned short bkt16[FILL_CH];  // 8 KB
  __shared__ unsigned char loc8[FILL_CH];    // 4 KB
  __shared__ int cntA[NB_MAX];               // 4 KB (becomes gbase)
  __shared__ int lbase[NB_MAX];              // 4 KB
  __shared__ int cntC[NB_MAX];               // 4 KB
  const int t = threadIdx.x;
  const int base = blockIdx.x * FILL_CH;
  const int edgesInBlock = min(FILL_CH, n_edges - base);

  for (int i = t; i < nb; i += 256) {
    cntA[i] = 0;
    cntC[i] = 0;
  }
  __syncthreads();

  // Phase A: count.
  for (int k = 0; k < FILL_CH / 256; ++k) {
    const int e = base + k * 256 + t;
    if (e < n_edges) atomicAdd(&cntA[esrc[e] >> 8], 1);
  }
  __syncthreads();

  // Phase B: exclusive scan of cntA -> lbase (segmented, K<=4 per thread).
  {
    __shared__ int part[256];
    const int K = (nb + 255) / 256;
    const int lo = t * K;
    const int hi = min(lo + K, nb);
    int sum = 0;
    for (int i = lo; i < hi; ++i) sum += cntA[i];
    part[t] = sum;
    __syncthreads();
    for (int o = 1; o < 256; o <<= 1) {
      const int tv = (t >= o) ? part[t - o] : 0;
      __syncthreads();
      part[t] += tv;
      __syncthreads();
    }
    int run = (t == 0) ? 0 : part[t - 1];
    for (int i = lo; i < hi; ++i) {
      lbase[i] = run;
      run += cntA[i];
    }
  }
  __syncthreads();
  // One RT atomic per nonempty bucket (consecutive addresses = fast path);
  // repurpose cntA as gbase.
  for (int i = t; i < nb; i += 256) {
    const int c = cntA[i];
    cntA[i] = c ? atomicAdd(&bucketCursor[i], c) : 0;
  }
  __syncthreads();

  // Phase C: re-read edges, rank within bucket, stage grouped in LDS.
  for (int k = 0; k < FILL_CH / 256; ++k) {
    const int e = base + k * 256 + t;
    if (e < n_edges) {
      const int s = esrc[e];
      const int b = s >> 8;
      const int r = atomicAdd(&cntC[b], 1);
      const int sp = lbase[b] + r;
      int2 pk;
      pk.x = edst[e];
      pk.y = __float_as_int(ew[e]);
      stage[sp] = pk;
      bkt16[sp] = (unsigned short)b;
      loc8[sp] = (unsigned char)(s & 255);
    }
  }
  __syncthreads();

  // Phase D: flush contiguous runs.
  for (int j = t; j < edgesInBlock; j += 256) {
    const int b = bkt16[j];
    const int pos = cntA[b] + (j - lbase[b]);
    sedge[pos] = stage[j];
    srcloc[pos] = loc8[j];
  }
}

// ---------------------------------------------------------------------------
// Bucket sort: one block per bucket; LDS counting sort by node-in-bucket.
// Pass1 counts; pass2 re-ranks (any rank permutation is valid) and places
// into sedge2 node-ordered. Also writes per-node off[].
// ---------------------------------------------------------------------------
__global__ __launch_bounds__(256) void bucket_sort_kernel(
    const int* __restrict__ bucketBase, const int2* __restrict__ sedge,
    const unsigned char* __restrict__ srcloc, int2* __restrict__ sedge2,
    int* __restrict__ off, int n_nodes) {
  __shared__ int cnt[NPB];      // 1 KB
  __shared__ int nodeOff[NPB];  // 1 KB
  const int t = threadIdx.x;
  const int beg = bucketBase[blockIdx.x];
  const int end = bucketBase[blockIdx.x + 1];
  const int nodeBase = blockIdx.x * NPB;
  const int nodesInBucket = min(NPB, n_nodes - nodeBase);

  cnt[t] = 0;
  __syncthreads();
  for (int j = beg + t; j < end; j += 256) atomicAdd(&cnt[srcloc[j]], 1);
  __syncthreads();
  // Exclusive scan of cnt (256 entries).
  {
    const int v = cnt[t];
    int s = v;
    nodeOff[t] = s;
    __syncthreads();
    for (int o = 1; o < 256; o <<= 1) {
      const int tv = (t >= o) ? nodeOff[t - o] : 0;
      __syncthreads();
      nodeOff[t] += tv;
      __syncthreads();
    }
    nodeOff[t] -= v;  // exclusive
  }
  if (t < nodesInBucket) off[nodeBase + t] = beg + nodeOff[t];
  cnt[t] = 0;
  __syncthreads();
  for (int j = beg + t; j < end; j += 256) {
    const int loc = srcloc[j];
    const int r = atomicAdd(&cnt[loc], 1);
    sedge2[beg + nodeOff[loc] + r] = sedge[j];
  }
}

// ---------------------------------------------------------------------------
// Gather (R6-proven, verbatim): one wave per node, register accumulation,
// bf16 rows, fused bias+relu.
// ---------------------------------------------------------------------------
__global__ __launch_bounds__(256) void gather_kernel(
    const int* __restrict__ off, const int2* __restrict__ sedge,
    const unsigned short* __restrict__ x0h, const float* __restrict__ b,
    float* __restrict__ out, int n_nodes) {
  const int wave = blockIdx.x * (blockDim.x >> 6) + (threadIdx.x >> 6);
  const int lane = threadIdx.x & 63;
  if (wave >= n_nodes) return;
  const int beg = off[wave];
  const int end = off[wave + 1];
  const unsigned* __restrict__ x0u = (const unsigned*)x0h;

  float2 a0 = {0.f, 0.f}, a1 = {0.f, 0.f};
  float2 a2 = {0.f, 0.f}, a3 = {0.f, 0.f};
  int e = beg;
  for (; e + 3 < end; e += 4) {
    const int2 e0 = sedge[e];
    const int2 e1 = sedge[e + 1];
    const int2 e2 = sedge[e + 2];
    const int2 e3 = sedge[e + 3];
    const unsigned u0 = x0u[(size_t)e0.x * 64 + lane];
    const unsigned u1 = x0u[(size_t)e1.x * 64 + lane];
    const unsigned u2 = x0u[(size_t)e2.x * 64 + lane];
    const unsigned u3 = x0u[(size_t)e3.x * 64 + lane];
    const float w0 = __int_as_float(e0.y);
    const float w1 = __int_as_float(e1.y);
    const float w2 = __int_as_float(e2.y);
    const float w3 = __int_as_float(e3.y);
    a0.x += __uint_as_float(u0 << 16) * w0;
    a0.y += __uint_as_float(u0 & 0xFFFF0000u) * w0;
    a1.x += __uint_as_float(u1 << 16) * w1;
    a1.y += __uint_as_float(u1 & 0xFFFF0000u) * w1;
    a2.x += __uint_as_float(u2 << 16) * w2;
    a2.y += __uint_as_float(u2 & 0xFFFF0000u) * w2;
    a3.x += __uint_as_float(u3 << 16) * w3;
    a3.y += __uint_as_float(u3 & 0xFFFF0000u) * w3;
  }
  for (; e < end; ++e) {
    const int2 e0 = sedge[e];
    const unsigned u0 = x0u[(size_t)e0.x * 64 + lane];
    const float w0 = __int_as_float(e0.y);
    a0.x += __uint_as_float(u0 << 16) * w0;
    a0.y += __uint_as_float(u0 & 0xFFFF0000u) * w0;
  }
  const float2 bb = ((const float2*)b)[lane];
  float2 r;
  r.x = fmaxf(a0.x + a1.x + a2.x + a3.x + bb.x, 0.f);
  r.y = fmaxf(a0.y + a1.y + a2.y + a3.y + bb.y, 0.f);
  ((float2*)out)[(size_t)wave * 64 + lane] = r;
}

// ---------------------------------------------------------------------------
// Fallback path (constraints violated): atomic scatter + epilogue.
// ---------------------------------------------------------------------------
__global__ __launch_bounds__(256) void scatter_kernel(
    const int* __restrict__ esrc, const int* __restrict__ edst,
    const float* __restrict__ ew, const unsigned short* __restrict__ x0h,
    float* __restrict__ acc, int n_edges) {
  const int lane = threadIdx.x & 63;
  const int waveId = blockIdx.x * (blockDim.x >> 6) + (threadIdx.x >> 6);
  const int nWaves = gridDim.x * (blockDim.x >> 6);
  const unsigned* __restrict__ x0u = (const unsigned*)x0h;
  for (int e = waveId; e < n_edges; e += nWaves) {
    const int s = esrc[e];
    const int d = edst[e];
    const float wt = ew[e];
    const unsigned u = x0u[(size_t)d * 64 + lane];
    float* p = acc + (size_t)s * H + lane * 2;
    atomicAdd(p, __uint_as_float(u << 16) * wt);
    atomicAdd(p + 1, __uint_as_float(u & 0xFFFF0000u) * wt);
  }
}

__global__ __launch_bounds__(256) void epilogue_kernel(
    float* __restrict__ out, const float* __restrict__ b, int n4) {
  const int i = blockIdx.x * blockDim.x + threadIdx.x;
  if (i >= n4) return;
  float4* o4 = (float4*)out;
  const float4* b4 = (const float4*)b;
  float4 v = o4[i];
  const float4 bb = b4[i & 31];
  v.x = fmaxf(v.x + bb.x, 0.f);
  v.y = fmaxf(v.y + bb.y, 0.f);
  v.z = fmaxf(v.z + bb.z, 0.f);
  v.w = fmaxf(v.w + bb.w, 0.f);
  o4[i] = v;
}

extern "C" void kernel_launch(void* const* d_in, const int* in_sizes, int n_in,
                              void* d_out, int out_size, void* d_ws, size_t ws_size,
                              hipStream_t stream) {
  const float* notes = (const float*)d_in[0];
  const float* w     = (const float*)d_in[1];
  const float* b     = (const float*)d_in[2];
  const int*   esrc  = (const int*)d_in[3];
  const int*   edst  = (const int*)d_in[4];
  const float* ew    = (const float*)d_in[5];
  const int*   gptr  = (const int*)d_in[6];

  const int n_nodes = in_sizes[0] / H;
  const int n_edges = in_sizes[3];
  float* out = (float*)d_out;

  const int nb = (n_nodes + NPB - 1) / NPB;

  // Workspace carve-up (256B-aligned regions).
  char* ws = (char*)d_ws;
  size_t p = 0;
  auto alloc = [&](size_t bytes) -> char* {
    char* cur = ws + p;
    p = (p + bytes + 255) & ~(size_t)255;
    return cur;
  };
  unsigned short* x0h = (unsigned short*)alloc((size_t)n_nodes * H * 2);
  int*  bucketCount  = (int*)alloc((size_t)nb * sizeof(int));
  int*  bucketBase   = (int*)alloc(((size_t)nb + 1) * sizeof(int));
  int*  bucketCursor = (int*)alloc((size_t)nb * sizeof(int));
  int*  off          = (int*)alloc(((size_t)n_nodes + 1) * sizeof(int));
  int2* sedge        = (int2*)alloc((size_t)n_edges * sizeof(int2));
  int2* sedge2       = (int2*)alloc((size_t)n_edges * sizeof(int2));
  unsigned char* srcloc = (unsigned char*)alloc((size_t)n_edges);
  const bool ok = (p <= ws_size) && (nb <= NB_MAX);

  // GEMM (also writes concat tail rows fp32; x0 stored bf16).
  gemm_kernel<<<(n_nodes + 63) / 64, 256, 0, stream>>>(notes, w, gptr, x0h, out,
                                                       n_nodes);

  if (ok) {
    hipMemsetAsync(bucketCount, 0, (size_t)nb * sizeof(int), stream);
    bucket_count_kernel<<<256, 256, 0, stream>>>(esrc, bucketCount, n_edges,
                                                 nb);
    bucket_scan_kernel<<<1, 256, 0, stream>>>(bucketCount, bucketBase,
                                              bucketCursor, off, nb, n_nodes,
                                              n_edges);
    bucket_fill_kernel<<<(n_edges + FILL_CH - 1) / FILL_CH, 256, 0, stream>>>(
        esrc, edst, ew, bucketCursor, sedge, srcloc, n_edges, nb);
    bucket_sort_kernel<<<nb, 256, 0, stream>>>(bucketBase, sedge, srcloc,
                                               sedge2, off, n_nodes);
    gather_kernel<<<(n_nodes + 3) / 4, 256, 0, stream>>>(off, sedge2, x0h, b,
                                                         out, n_nodes);
  } else {
    hipMemsetAsync(d_out, 0, (size_t)n_nodes * H * sizeof(float), stream);
    scatter_kernel<<<2048, 256, 0, stream>>>(esrc, edst, ew, x0h, out, n_edges);
    const int n4 = n_nodes * H / 4;
    epilogue_kernel<<<(n4 + 255) / 256, 256, 0, stream>>>(out, b, n4);
  }
}